// Round 3
// baseline (460.514 us; speedup 1.0000x reference)
//
#include <hip/hip_runtime.h>
#include <hip/hip_fp16.h>
#include <cstdint>
#include <cstddef>

// Problem constants (fixed by the reference generator)
#define DD 64           // feature dim D == A
#define N_RELTAB 401    // rel_emb rows
#define N_QR 8          // batchsize B
#define T_ROWS (N_RELTAB + N_QR)   // 409 f32 rows: C[0..400], Q[401..408]
#define WPB 4           // waves per block in fused_aggregate

// K0: Cf[r] = Wr . rel_emb[r]                      (r < 401)
//     Cf[401+k] = Wqr . rel_emb[q_rel[k]] + Wqr_b  (k < 8)   (all f32)
__global__ __launch_bounds__(64) void build_C(
    const float* __restrict__ rel_emb, const float* __restrict__ Wr,
    const float* __restrict__ Wqr_w, const float* __restrict__ Wqr_b,
    const int* __restrict__ q_rel, float* __restrict__ Cf)
{
    int r = blockIdx.x, a = threadIdx.x;
    const float* w; const float* src; float acc;
    if (r < N_RELTAB) { w = Wr + a * DD; src = rel_emb + r * DD; acc = 0.f; }
    else {
        int k = r - N_RELTAB;
        w = Wqr_w + a * DD;
        src = rel_emb + q_rel[k] * DD;   // block-uniform
        acc = Wqr_b[a];
    }
#pragma unroll
    for (int d = 0; d < DD; ++d) acc = fmaf(src[d], w[d], acc);
    Cf[r * DD + a] = acc;
}

// Row-per-lane matvec: out[n][a] = sum_d in[n][d] * W[a][d].
__global__ __launch_bounds__(256) void rowmat(
    const float* __restrict__ in, const float* __restrict__ W,
    float* __restrict__ out, int nrows)
{
    int n = blockIdx.x * 256 + threadIdx.x;
    if (n >= nrows) return;
    float row[DD];
    const float4* rp = (const float4*)(in + ((size_t)n << 6));
#pragma unroll
    for (int j = 0; j < DD / 4; ++j) {
        float4 v = rp[j];
        row[4*j+0] = v.x; row[4*j+1] = v.y; row[4*j+2] = v.z; row[4*j+3] = v.w;
    }
    float4* op = (float4*)(out + ((size_t)n << 6));
    for (int a0 = 0; a0 < DD; a0 += 4) {
        const float* w0 = W + a0 * DD;
        float s0 = 0.f, s1 = 0.f, s2 = 0.f, s3 = 0.f;
#pragma unroll
        for (int d = 0; d < DD; ++d) {
            float r = row[d];
            s0 = fmaf(w0[d],          r, s0);
            s1 = fmaf(w0[DD + d],     r, s1);
            s2 = fmaf(w0[2 * DD + d], r, s2);
            s3 = fmaf(w0[3 * DD + d], r, s3);
        }
        float4 o; o.x = s0; o.y = s1; o.z = s2; o.w = s3;
        op[a0 >> 2] = o;
    }
}

// K1: histogram of obj
__global__ __launch_bounds__(256) void hist_kernel(
    const int* __restrict__ edges, int* __restrict__ counts, int n_edge)
{
    int e = blockIdx.x * 256 + threadIdx.x;
    if (e < n_edge) atomicAdd(&counts[edges[6 * e + 5]], 1);
}

// K2: per-chunk exclusive scan (chunk = 1024), block-local excl + block sums
__global__ __launch_bounds__(1024) void scan1(
    const int* __restrict__ counts, int* __restrict__ offsets,
    int* __restrict__ bsums, int n)
{
    __shared__ int wsum[16];
    int t = threadIdx.x, i = blockIdx.x * 1024 + t;
    int lane = t & 63, wid = t >> 6;
    int c = (i < n) ? counts[i] : 0;
    int v = c;
#pragma unroll
    for (int d = 1; d < 64; d <<= 1) { int u = __shfl_up(v, d); if (lane >= d) v += u; }
    if (lane == 63) wsum[wid] = v;
    __syncthreads();
    if (wid == 0) {
        int s = (lane < 16) ? wsum[lane] : 0;
#pragma unroll
        for (int d = 1; d < 16; d <<= 1) { int u = __shfl_up(s, d); if (lane >= d) s += u; }
        if (lane < 16) wsum[lane] = s;
    }
    __syncthreads();
    int woff = (wid == 0) ? 0 : wsum[wid - 1];
    if (i < n) offsets[i] = woff + v - c;
    if (t == 1023) bsums[blockIdx.x] = wsum[15];
}

// K3: parallel single-block exclusive scan of block sums (nb <= 1024)
__global__ __launch_bounds__(1024) void scan_small(
    const int* __restrict__ bsums, int* __restrict__ boffs, int nb)
{
    __shared__ int wsum[16];
    int t = threadIdx.x, lane = t & 63, wid = t >> 6;
    int c = (t < nb) ? bsums[t] : 0;
    int v = c;
#pragma unroll
    for (int d = 1; d < 64; d <<= 1) { int u = __shfl_up(v, d); if (lane >= d) v += u; }
    if (lane == 63) wsum[wid] = v;
    __syncthreads();
    if (wid == 0) {
        int s = (lane < 16) ? wsum[lane] : 0;
#pragma unroll
        for (int d = 1; d < 16; d <<= 1) { int u = __shfl_up(s, d); if (lane >= d) s += u; }
        if (lane < 16) wsum[lane] = s;
    }
    __syncthreads();
    int woff = (wid == 0) ? 0 : wsum[wid - 1];
    if (t < nb) boffs[t] = woff + v - c;
}

// K4: add block offsets; init cursor = offsets
__global__ __launch_bounds__(1024) void scan3(
    int* __restrict__ offsets, int* __restrict__ cursor,
    const int* __restrict__ boffs, int n)
{
    int i = blockIdx.x * 1024 + threadIdx.x;
    if (i < n) {
        int v = offsets[i] + boffs[blockIdx.x];
        offsets[i] = v;
        cursor[i] = v;
    }
}

// K5: counting-sort edges by obj; u64 = payload(low32: sub17|rel9|ridx3) | obj<<32
__global__ __launch_bounds__(256) void build_sorted(
    const int* __restrict__ edges, int* __restrict__ cursor,
    uint64_t* __restrict__ sorted, int n_edge)
{
    int e = blockIdx.x * 256 + threadIdx.x;
    if (e >= n_edge) return;
    const int2* ep = (const int2*)(edges + 6 * e);
    int ridx = ep[0].x;
    int rel  = ep[1].x;
    int2 so  = ep[2];        // sub, obj
    int pos = atomicAdd(&cursor[so.y], 1);
    uint32_t pay = (uint32_t)so.x | ((uint32_t)rel << 17) | ((uint32_t)ridx << 26);
    sorted[pos] = (uint64_t)pay | ((uint64_t)(uint32_t)so.y << 32);
}

// K6: fused alpha + segmented aggregation over obj-sorted edges.
// One wave per 64 edges. Phase A (lane=feature): products -> LDS (f16).
// Phase B (lane=edge): row-sum -> per-lane dot; vectorized sigmoid.
// Phase C (lane=feature): segmented accumulate, store interior / atomic boundary.
__global__ __launch_bounds__(64 * WPB) void fused_aggregate(
    const uint64_t* __restrict__ sorted, const float* __restrict__ X,
    const float* __restrict__ hidden, const float* __restrict__ Cf,
    const float* __restrict__ rel_emb, const float* __restrict__ walpha_w,
    const float* __restrict__ walpha_b, float* __restrict__ agg,
    int n_edge, int n_node)
{
    __shared__ float sQ[N_QR * DD];            // 2 KB
    __shared__ uint2 hdr[WPB][DD];             // 2 KB  (payload, obj)
    __shared__ __half sS[WPB][DD][DD + 2];     // 33.8 KB, stride 66 halves
    int tid = threadIdx.x;
    int lane = tid & 63, wid = tid >> 6;
    for (int i = tid; i < N_QR * DD; i += 64 * WPB) sQ[i] = Cf[N_RELTAB * DD + i];

    long wchunk = (long)blockIdx.x * WPB + wid;
    long e = wchunk * DD + lane;
    uint64_t p = (e < n_edge) ? sorted[e]
                              : ((uint64_t)(uint32_t)n_node << 32);  // sentinel obj
    hdr[wid][lane] = make_uint2((uint32_t)p, (uint32_t)(p >> 32));
    __syncthreads();

    float wa = walpha_w[lane];
    float wb = walpha_b[0];

    // ---- Phase A: per-edge feature products (independent iterations) ----
#pragma unroll 4
    for (int j = 0; j < DD; ++j) {
        uint32_t pj = __builtin_amdgcn_readfirstlane(hdr[wid][j].x);
        int sub  = (int)(pj & 0x1FFFFu);
        int rel  = (int)((pj >> 17) & 0x1FFu);
        int ridx = (int)((pj >> 26) & 7u);
        float x = X[((size_t)sub << 6) + lane];
        float c = Cf[(rel << 6) + lane];
        float q = sQ[(ridx << 6) + lane];
        sS[wid][j][lane] = __float2half(fmaxf(x + c + q, 0.f) * wa);
    }
    __syncthreads();

    // ---- Phase B: lane l = edge l; sum its 64 products ----
    float t = 0.f;
    const __half2* row2 = (const __half2*)&sS[wid][lane][0];
#pragma unroll
    for (int a2 = 0; a2 < DD / 2; ++a2) {
        float2 f = __half22float2(row2[a2]);
        t += f.x + f.y;
    }
    float alpha_l = 1.f / (1.f + __expf(-(t + wb)));   // alpha for edge (chunk,lane)

    // ---- Phase C: segmented aggregation (lane = feature) ----
    float acc = 0.f;
    int prev = (int)__builtin_amdgcn_readfirstlane(hdr[wid][0].y);
    bool firstseg = true;
    for (int j = 0; j < DD; ++j) {
        uint32_t pj = __builtin_amdgcn_readfirstlane(hdr[wid][j].x);
        int oj      = (int)__builtin_amdgcn_readfirstlane(hdr[wid][j].y);
        if (oj != prev) {
            if (prev < n_node) {
                if (firstseg) atomicAdd(&agg[((size_t)prev << 6) + lane], acc);
                else          agg[((size_t)prev << 6) + lane] = acc;
            }
            firstseg = false;
            acc = 0.f;
            prev = oj;
        }
        if (oj < n_node) {
            int sub = (int)(pj & 0x1FFFFu);
            int rel = (int)((pj >> 17) & 0x1FFu);
            float h = hidden[((size_t)sub << 6) + lane];
            float r = rel_emb[(rel << 6) + lane];
            float aj = __uint_as_float(__builtin_amdgcn_readlane(__float_as_uint(alpha_l), j));
            acc = fmaf(aj, h + r, acc);
        }
    }
    if (prev < n_node) atomicAdd(&agg[((size_t)prev << 6) + lane], acc);
}

extern "C" void kernel_launch(void* const* d_in, const int* in_sizes, int n_in,
                              void* d_out, int out_size, void* d_ws, size_t ws_size,
                              hipStream_t stream)
{
    const int*   q_rel    = (const int*)d_in[1];
    const float* hidden   = (const float*)d_in[2];
    const int*   edges    = (const int*)d_in[3];
    const float* rel_emb  = (const float*)d_in[7];
    const float* Ws       = (const float*)d_in[8];
    const float* Wr       = (const float*)d_in[9];
    const float* Wqr_w    = (const float*)d_in[10];
    const float* Wqr_b    = (const float*)d_in[11];
    const float* walpha_w = (const float*)d_in[12];
    const float* walpha_b = (const float*)d_in[13];
    const float* Wh       = (const float*)d_in[14];
    float* out = (float*)d_out;

    const int n_node = in_sizes[2] / DD;   // 100000
    const int n_edge = in_sizes[3] / 6;    // 1000000
    const int NB = (n_node + 1023) / 1024; // scan chunks (98)

    // ws layout (all segment sizes multiples of 64 B):
    char* w = (char*)d_ws;
    float*    X       = (float*)w;     w += (size_t)n_node * DD * 4;   // 25.6 MB
    float*    agg     = (float*)w;     w += (size_t)n_node * DD * 4;   // 25.6 MB
    uint64_t* sorted  = (uint64_t*)w;  w += (size_t)n_edge * 8;        // 8 MB
    int*      counts  = (int*)w;       w += (size_t)n_node * 4;
    int*      offsets = (int*)w;       w += (size_t)n_node * 4;
    int*      cursor  = (int*)w;       w += (size_t)n_node * 4;
    int*      bsums   = (int*)w;       w += 4096;
    int*      boffs   = (int*)w;       w += 4096;
    float*    Cf      = (float*)w;     w += (size_t)T_ROWS * DD * 4;   // 104.7 KB

    build_C<<<T_ROWS, 64, 0, stream>>>(rel_emb, Wr, Wqr_w, Wqr_b, q_rel, Cf);
    rowmat<<<(n_node + 255) / 256, 256, 0, stream>>>(hidden, Ws, X, n_node);
    hipMemsetAsync(counts, 0, (size_t)n_node * 4, stream);
    hipMemsetAsync(agg, 0, (size_t)n_node * DD * 4, stream);
    hist_kernel<<<(n_edge + 255) / 256, 256, 0, stream>>>(edges, counts, n_edge);
    scan1<<<NB, 1024, 0, stream>>>(counts, offsets, bsums, n_node);
    scan_small<<<1, 1024, 0, stream>>>(bsums, boffs, NB);
    scan3<<<NB, 1024, 0, stream>>>(offsets, cursor, boffs, n_node);
    build_sorted<<<(n_edge + 255) / 256, 256, 0, stream>>>(edges, cursor, sorted, n_edge);
    const int nwaves = (n_edge + DD - 1) / DD;              // 15625
    fused_aggregate<<<(nwaves + WPB - 1) / WPB, 64 * WPB, 0, stream>>>(
        sorted, X, hidden, Cf, rel_emb, walpha_w, walpha_b, agg, n_edge, n_node);
    rowmat<<<(n_node + 255) / 256, 256, 0, stream>>>(agg, Wh, out, n_node);
}

// Round 5
// 428.278 us; speedup vs baseline: 1.0753x; 1.0753x over previous
//
#include <hip/hip_runtime.h>
#include <hip/hip_fp16.h>
#include <cstdint>
#include <cstddef>

// Problem constants (fixed by the reference generator)
#define DD 64           // feature dim D == A
#define N_RELTAB 401    // rel_emb rows
#define N_QR 8          // batchsize B
#define T_ROWS (N_RELTAB + N_QR)   // 409 f32 rows: C[0..400], Q[401..408]
#define CHUNK 32        // edges per wave in fused_aggregate
#define WPB 4           // waves per block in fused_aggregate

__device__ __forceinline__ uint16_t f2bf(float f) {
    uint32_t u = __float_as_uint(f);
    u += 0x7fffu + ((u >> 16) & 1u);     // RNE
    return (uint16_t)(u >> 16);
}
__device__ __forceinline__ float bf2f(uint16_t u) {
    return __uint_as_float(((uint32_t)u) << 16);
}

// K0: Cf[r] = Wr . rel_emb[r]                      (r < 401)
//     Cf[401+k] = Wqr . rel_emb[q_rel[k]] + Wqr_b  (k < 8)   (all f32)
__global__ __launch_bounds__(64) void build_C(
    const float* __restrict__ rel_emb, const float* __restrict__ Wr,
    const float* __restrict__ Wqr_w, const float* __restrict__ Wqr_b,
    const int* __restrict__ q_rel, float* __restrict__ Cf)
{
    int r = blockIdx.x, a = threadIdx.x;
    const float* w; const float* src; float acc;
    if (r < N_RELTAB) { w = Wr + a * DD; src = rel_emb + r * DD; acc = 0.f; }
    else {
        int k = r - N_RELTAB;
        w = Wqr_w + a * DD;
        src = rel_emb + q_rel[k] * DD;   // block-uniform
        acc = Wqr_b[a];
    }
#pragma unroll
    for (int d = 0; d < DD; ++d) acc = fmaf(src[d], w[d], acc);
    Cf[r * DD + a] = acc;
}

// LDS-staged row matvec: out[n][a] = sum_d in[n][d] * W[a][d].
// 64 rows / block of 256; coalesced stage-in, LDS row reads (2-way free),
// LDS-restaged coalesced store. BF16OUT: pack bf16 pairs.
template<bool BF16OUT>
__global__ __launch_bounds__(256) void rowmat_t(
    const float* __restrict__ in, const float* __restrict__ W,
    void* __restrict__ outv, int nrows)
{
    __shared__ float sIn[DD][DD + 1];   // 16.6 KB; reused for out staging
    int r0 = blockIdx.x * DD;
    int t = threadIdx.x;
    int vr = nrows - r0; if (vr > DD) vr = DD;

    // stage-in: 1024 float4, coalesced
    const float4* gin = (const float4*)(in + (size_t)r0 * DD);
    int vf4 = vr * (DD / 4);
#pragma unroll
    for (int k = 0; k < 4; ++k) {
        int f = t + k * 256;
        float4 v = (f < vf4) ? gin[f] : make_float4(0.f, 0.f, 0.f, 0.f);
        int row = f >> 4, c4 = (f & 15) * 4;
        sIn[row][c4] = v.x; sIn[row][c4+1] = v.y; sIn[row][c4+2] = v.z; sIn[row][c4+3] = v.w;
    }
    __syncthreads();

    int row = t & 63, q = t >> 6;       // thread = (row, col-quarter)
    float acc[16];
#pragma unroll
    for (int c = 0; c < 16; ++c) acc[c] = 0.f;
    const float* wq = W + (q * 16) * DD;
    for (int d4 = 0; d4 < 16; ++d4) {
        float a0 = sIn[row][4*d4+0], a1 = sIn[row][4*d4+1];
        float a2 = sIn[row][4*d4+2], a3 = sIn[row][4*d4+3];
#pragma unroll
        for (int c = 0; c < 16; ++c) {
            const float* wr = wq + c * DD + d4 * 4;   // wave-uniform -> s_load
            acc[c] = fmaf(a0, wr[0], acc[c]);
            acc[c] = fmaf(a1, wr[1], acc[c]);
            acc[c] = fmaf(a2, wr[2], acc[c]);
            acc[c] = fmaf(a3, wr[3], acc[c]);
        }
    }
    __syncthreads();                    // done reading sIn

    if (BF16OUT) {
        uint32_t (*sOutU)[33] = (uint32_t (*)[33])&sIn[0][0];  // 8.4 KB view
#pragma unroll
        for (int c2 = 0; c2 < 8; ++c2)
            sOutU[row][q * 8 + c2] =
                (uint32_t)f2bf(acc[2*c2]) | ((uint32_t)f2bf(acc[2*c2+1]) << 16);
        __syncthreads();
        uint32_t* outU = (uint32_t*)outv;
        int vu = vr * (DD / 2);
#pragma unroll
        for (int k = 0; k < 8; ++k) {
            int u = t + k * 256;
            if (u < vu) outU[(size_t)r0 * (DD / 2) + u] = sOutU[u >> 5][u & 31];
        }
    } else {
#pragma unroll
        for (int c = 0; c < 16; ++c) sIn[row][q * 16 + c] = acc[c];
        __syncthreads();
        float4* out4 = (float4*)outv;
        int vf = vr * (DD / 4);
#pragma unroll
        for (int k = 0; k < 4; ++k) {
            int f = t + k * 256;
            if (f < vf) {
                int rr = f >> 4, c4 = (f & 15) * 4;
                float4 v;
                v.x = sIn[rr][c4]; v.y = sIn[rr][c4+1];
                v.z = sIn[rr][c4+2]; v.w = sIn[rr][c4+3];
                out4[(size_t)r0 * (DD / 4) + f] = v;
            }
        }
    }
}

// K1: histogram of obj + emit compact keys (pay | obj<<32)
__global__ __launch_bounds__(256) void hist_emit(
    const int* __restrict__ edges, int* __restrict__ counts,
    uint64_t* __restrict__ keys, int n_edge)
{
    int e = blockIdx.x * 256 + threadIdx.x;
    if (e >= n_edge) return;
    const int2* ep = (const int2*)(edges + 6 * e);
    int ridx = ep[0].x;
    int rel  = ep[1].x;
    int2 so  = ep[2];        // sub, obj
    atomicAdd(&counts[so.y], 1);
    uint32_t pay = (uint32_t)so.x | ((uint32_t)rel << 17) | ((uint32_t)ridx << 26);
    keys[e] = (uint64_t)pay | ((uint64_t)(uint32_t)so.y << 32);
}

// K2: per-chunk exclusive scan (chunk = 1024), block-local excl + block sums
__global__ __launch_bounds__(1024) void scan1(
    const int* __restrict__ counts, int* __restrict__ offsets,
    int* __restrict__ bsums, int n)
{
    __shared__ int wsum[16];
    int t = threadIdx.x, i = blockIdx.x * 1024 + t;
    int lane = t & 63, wid = t >> 6;
    int c = (i < n) ? counts[i] : 0;
    int v = c;
#pragma unroll
    for (int d = 1; d < 64; d <<= 1) { int u = __shfl_up(v, d); if (lane >= d) v += u; }
    if (lane == 63) wsum[wid] = v;
    __syncthreads();
    if (wid == 0) {
        int s = (lane < 16) ? wsum[lane] : 0;
#pragma unroll
        for (int d = 1; d < 16; d <<= 1) { int u = __shfl_up(s, d); if (lane >= d) s += u; }
        if (lane < 16) wsum[lane] = s;
    }
    __syncthreads();
    int woff = (wid == 0) ? 0 : wsum[wid - 1];
    if (i < n) offsets[i] = woff + v - c;
    if (t == 1023) bsums[blockIdx.x] = wsum[15];
}

// K3: parallel single-block exclusive scan of block sums (nb <= 1024)
__global__ __launch_bounds__(1024) void scan_small(
    const int* __restrict__ bsums, int* __restrict__ boffs, int nb)
{
    __shared__ int wsum[16];
    int t = threadIdx.x, lane = t & 63, wid = t >> 6;
    int c = (t < nb) ? bsums[t] : 0;
    int v = c;
#pragma unroll
    for (int d = 1; d < 64; d <<= 1) { int u = __shfl_up(v, d); if (lane >= d) v += u; }
    if (lane == 63) wsum[wid] = v;
    __syncthreads();
    if (wid == 0) {
        int s = (lane < 16) ? wsum[lane] : 0;
#pragma unroll
        for (int d = 1; d < 16; d <<= 1) { int u = __shfl_up(s, d); if (lane >= d) s += u; }
        if (lane < 16) wsum[lane] = s;
    }
    __syncthreads();
    int woff = (wid == 0) ? 0 : wsum[wid - 1];
    if (t < nb) boffs[t] = woff + v - c;
}

// K4: add block offsets; init cursor
__global__ __launch_bounds__(1024) void scan3(
    int* __restrict__ offsets, int* __restrict__ cursor,
    const int* __restrict__ boffs, int n)
{
    int i = blockIdx.x * 1024 + threadIdx.x;
    if (i < n) {
        int v = offsets[i] + boffs[blockIdx.x];
        offsets[i] = v;
        cursor[i] = v;
    }
}

// K5: counting-sort from compact keys
__global__ __launch_bounds__(256) void build_sorted(
    const uint64_t* __restrict__ keys, int* __restrict__ cursor,
    uint64_t* __restrict__ sorted, int n_edge)
{
    int e = blockIdx.x * 256 + threadIdx.x;
    if (e >= n_edge) return;
    uint64_t k = keys[e];
    int obj = (int)(k >> 32);
    int pos = atomicAdd(&cursor[obj], 1);
    sorted[pos] = k;
}

// K6: fused alpha + segmented aggregation. One wave per 32 obj-sorted edges.
// Headers live in lanes 0..31; per-edge scalars come from v_readlane (SALU).
// Phase A (lane=feature): products -> LDS f16.  Phase B (lane=edge&31,
// half=lane>>5): row-sum halves + one shfl -> alpha.  Phase C (lane=feature):
// segmented accumulate, plain store interior / atomic at chunk boundaries.
__global__ __launch_bounds__(256, 4) void fused_aggregate(
    const uint64_t* __restrict__ sorted, const uint16_t* __restrict__ Xb,
    const float* __restrict__ hidden, const float* __restrict__ Cf,
    const float* __restrict__ rel_emb, const float* __restrict__ walpha_w,
    const float* __restrict__ walpha_b, float* __restrict__ agg,
    int n_edge, int n_node)
{
    __shared__ float sQ[N_QR * DD];               // 2 KB
    __shared__ __half sS[WPB][CHUNK][DD + 2];     // 16.9 KB
    int tid = threadIdx.x, lane = tid & 63, wid = tid >> 6;
    for (int i = tid; i < N_QR * DD; i += 64 * WPB) sQ[i] = Cf[N_RELTAB * DD + i];
    __syncthreads();

    long chunk = (long)blockIdx.x * WPB + wid;
    long base = chunk * CHUNK;
    if (base >= n_edge) return;

    int e_l = (int)base + (lane & 31);
    uint64_t k = (lane < 32 && e_l < n_edge)
                     ? sorted[e_l]
                     : ((uint64_t)(uint32_t)n_node << 32);   // sentinel
    uint32_t pay = (uint32_t)k;
    int obj      = (int)(k >> 32);

    float wa = walpha_w[lane];
    float wb = walpha_b[0];

    // ---- Phase A ----
#pragma unroll 8
    for (int j = 0; j < CHUNK; ++j) {
        uint32_t pj = (uint32_t)__builtin_amdgcn_readlane((int)pay, j);
        int sub  = (int)(pj & 0x1FFFFu);
        int rel  = (int)((pj >> 17) & 0x1FFu);
        int ridx = (int)((pj >> 26) & 7u);
        float x = bf2f(Xb[((size_t)sub << 6) + lane]);
        float c = Cf[(rel << 6) + lane];
        float q = sQ[(ridx << 6) + lane];
        sS[wid][j][lane] = __float2half(fmaxf(x + c + q, 0.f) * wa);
    }

    // ---- Phase B ----
    int eb = lane & 31, hb = lane >> 5;
    const __half2* row2 = (const __half2*)&sS[wid][eb][hb * 32];
    float tsum = 0.f;
#pragma unroll
    for (int a2 = 0; a2 < 16; ++a2) {
        float2 f = __half22float2(row2[a2]);
        tsum += f.x + f.y;
    }
    tsum += __shfl_xor(tsum, 32);
    float alpha = 1.f / (1.f + __expf(-(tsum + wb)));   // lanes j, j+32 hold edge j

    // ---- Phase C ----
    float acc = 0.f;
    int prev = __builtin_amdgcn_readlane(obj, 0);
    bool first = true;
#pragma unroll 4
    for (int j = 0; j < CHUNK; ++j) {
        int oj = __builtin_amdgcn_readlane(obj, j);
        if (oj != prev) {
            if (prev < n_node) {
                float* dst = &agg[((size_t)prev << 6) + lane];
                if (first) atomicAdd(dst, acc); else *dst = acc;
            }
            first = false; acc = 0.f; prev = oj;
        }
        if (oj < n_node) {
            uint32_t pj = (uint32_t)__builtin_amdgcn_readlane((int)pay, j);
            int sub = (int)(pj & 0x1FFFFu);
            int rel = (int)((pj >> 17) & 0x1FFu);
            float h = hidden[((size_t)sub << 6) + lane];
            float r = rel_emb[(rel << 6) + lane];
            float aj = __uint_as_float(
                (uint32_t)__builtin_amdgcn_readlane((int)__float_as_uint(alpha), j));
            acc = fmaf(aj, h + r, acc);
        }
    }
    if (prev < n_node) atomicAdd(&agg[((size_t)prev << 6) + lane], acc);
}

extern "C" void kernel_launch(void* const* d_in, const int* in_sizes, int n_in,
                              void* d_out, int out_size, void* d_ws, size_t ws_size,
                              hipStream_t stream)
{
    const int*   q_rel    = (const int*)d_in[1];
    const float* hidden   = (const float*)d_in[2];
    const int*   edges    = (const int*)d_in[3];
    const float* rel_emb  = (const float*)d_in[7];
    const float* Ws       = (const float*)d_in[8];
    const float* Wr       = (const float*)d_in[9];
    const float* Wqr_w    = (const float*)d_in[10];
    const float* Wqr_b    = (const float*)d_in[11];
    const float* walpha_w = (const float*)d_in[12];
    const float* walpha_b = (const float*)d_in[13];
    const float* Wh       = (const float*)d_in[14];
    float* out = (float*)d_out;

    const int n_node = in_sizes[2] / DD;   // 100000
    const int n_edge = in_sizes[3] / 6;    // 1000000
    const int NB = (n_node + 1023) / 1024; // scan chunks (98)

    // ws layout (all segments 64 B multiples):
    char* w = (char*)d_ws;
    uint16_t* Xb      = (uint16_t*)w;  w += (size_t)n_node * DD * 2;   // 12.8 MB
    float*    agg     = (float*)w;     w += (size_t)n_node * DD * 4;   // 25.6 MB
    uint64_t* sorted  = (uint64_t*)w;  w += (size_t)n_edge * 8;        // 8 MB
    uint64_t* keys    = (uint64_t*)w;  w += (size_t)n_edge * 8;        // 8 MB
    int*      counts  = (int*)w;       w += (size_t)n_node * 4;
    int*      offsets = (int*)w;       w += (size_t)n_node * 4;
    int*      cursor  = (int*)w;       w += (size_t)n_node * 4;
    int*      bsums   = (int*)w;       w += 4096;
    int*      boffs   = (int*)w;       w += 4096;
    float*    Cf      = (float*)w;     w += (size_t)T_ROWS * DD * 4;   // 104.7 KB

    build_C<<<T_ROWS, 64, 0, stream>>>(rel_emb, Wr, Wqr_w, Wqr_b, q_rel, Cf);
    rowmat_t<true><<<(n_node + DD - 1) / DD, 256, 0, stream>>>(hidden, Ws, Xb, n_node);
    hipMemsetAsync(counts, 0, (size_t)n_node * 4, stream);
    hipMemsetAsync(agg, 0, (size_t)n_node * DD * 4, stream);
    hist_emit<<<(n_edge + 255) / 256, 256, 0, stream>>>(edges, counts, keys, n_edge);
    scan1<<<NB, 1024, 0, stream>>>(counts, offsets, bsums, n_node);
    scan_small<<<1, 1024, 0, stream>>>(bsums, boffs, NB);
    scan3<<<NB, 1024, 0, stream>>>(offsets, cursor, boffs, n_node);
    build_sorted<<<(n_edge + 255) / 256, 256, 0, stream>>>(keys, cursor, sorted, n_edge);
    const int nchunks = (n_edge + CHUNK - 1) / CHUNK;       // 31250
    fused_aggregate<<<(nchunks + WPB - 1) / WPB, 64 * WPB, 0, stream>>>(
        sorted, Xb, hidden, Cf, rel_emb, walpha_w, walpha_b, agg, n_edge, n_node);
    rowmat_t<false><<<(n_node + DD - 1) / DD, 256, 0, stream>>>(agg, Wh, out, n_node);
}

// Round 6
// 421.609 us; speedup vs baseline: 1.0923x; 1.0158x over previous
//
#include <hip/hip_runtime.h>
#include <hip/hip_fp16.h>
#include <cstdint>
#include <cstddef>

// Problem constants (fixed by the reference generator)
#define DD 64           // feature dim D == A
#define N_RELTAB 401    // rel_emb rows
#define N_QR 8          // batchsize B
#define T_ROWS (N_RELTAB + N_QR)   // 409 f32 rows: C[0..400], Q[401..408]
#define CHUNK 32        // edges per wave in fused_aggregate
#define WPB 4           // waves per block in fused_aggregate

__device__ __forceinline__ uint16_t f2bf(float f) {
    uint32_t u = __float_as_uint(f);
    u += 0x7fffu + ((u >> 16) & 1u);     // RNE
    return (uint16_t)(u >> 16);
}
__device__ __forceinline__ float bf2f(uint16_t u) {
    return __uint_as_float(((uint32_t)u) << 16);
}

// K0: Cf[r]  = Wr . rel_emb[r]                      (r < 401)
//     Cf[401+k] = Wqr . rel_emb[q_rel[k]] + Wqr_b   (k < 8)
//     RWh[r] = Wh . rel_emb[r]                      (r < 401)   (all f32)
__global__ __launch_bounds__(64) void build_tables(
    const float* __restrict__ rel_emb, const float* __restrict__ Wr,
    const float* __restrict__ Wqr_w, const float* __restrict__ Wqr_b,
    const int* __restrict__ q_rel, const float* __restrict__ Wh,
    float* __restrict__ Cf, float* __restrict__ RWh)
{
    int r = blockIdx.x, a = threadIdx.x;
    if (r < N_RELTAB) {
        const float* src = rel_emb + r * DD;
        const float* w1 = Wr + a * DD;
        const float* w2 = Wh + a * DD;
        float a1 = 0.f, a2 = 0.f;
#pragma unroll
        for (int d = 0; d < DD; ++d) {
            float s = src[d];
            a1 = fmaf(s, w1[d], a1);
            a2 = fmaf(s, w2[d], a2);
        }
        Cf[r * DD + a] = a1;
        RWh[r * DD + a] = a2;
    } else {
        int k = r - N_RELTAB;
        const float* src = rel_emb + q_rel[k] * DD;  // block-uniform
        const float* w = Wqr_w + a * DD;
        float acc = Wqr_b[a];
#pragma unroll
        for (int d = 0; d < DD; ++d) acc = fmaf(src[d], w[d], acc);
        Cf[r * DD + a] = acc;
    }
}

// K1: single pass over hidden -> Xb (bf16, Ws.h) and HWh (f32, Wh.h).
// 64 rows / block of 256; coalesced stage-in via LDS, wave-uniform W (s_load),
// LDS-restaged coalesced stores.
__global__ __launch_bounds__(256) void prep(
    const float* __restrict__ in, const float* __restrict__ Ws,
    const float* __restrict__ Wh, uint16_t* __restrict__ Xb,
    float* __restrict__ HWh, int nrows)
{
    __shared__ float sIn[DD][DD + 1];   // 16.6 KB; reused for out staging
    int r0 = blockIdx.x * DD;
    int t = threadIdx.x;
    int vr = nrows - r0; if (vr > DD) vr = DD;

    const float4* gin = (const float4*)(in + (size_t)r0 * DD);
    int vf4 = vr * (DD / 4);
#pragma unroll
    for (int k = 0; k < 4; ++k) {
        int f = t + k * 256;
        float4 v = (f < vf4) ? gin[f] : make_float4(0.f, 0.f, 0.f, 0.f);
        int row = f >> 4, c4 = (f & 15) * 4;
        sIn[row][c4] = v.x; sIn[row][c4+1] = v.y; sIn[row][c4+2] = v.z; sIn[row][c4+3] = v.w;
    }
    __syncthreads();

    int row = t & 63, q = t >> 6;       // thread = (row, col-quarter)
    float accX[16], accH[16];
#pragma unroll
    for (int c = 0; c < 16; ++c) { accX[c] = 0.f; accH[c] = 0.f; }
    const float* wqX = Ws + (q * 16) * DD;
    const float* wqH = Wh + (q * 16) * DD;
    for (int d4 = 0; d4 < 16; ++d4) {
        float a0 = sIn[row][4*d4+0], a1 = sIn[row][4*d4+1];
        float a2 = sIn[row][4*d4+2], a3 = sIn[row][4*d4+3];
#pragma unroll
        for (int c = 0; c < 16; ++c) {
            const float* wx = wqX + c * DD + d4 * 4;   // wave-uniform -> s_load
            const float* wh = wqH + c * DD + d4 * 4;
            accX[c] = fmaf(a0, wx[0], accX[c]);
            accX[c] = fmaf(a1, wx[1], accX[c]);
            accX[c] = fmaf(a2, wx[2], accX[c]);
            accX[c] = fmaf(a3, wx[3], accX[c]);
            accH[c] = fmaf(a0, wh[0], accH[c]);
            accH[c] = fmaf(a1, wh[1], accH[c]);
            accH[c] = fmaf(a2, wh[2], accH[c]);
            accH[c] = fmaf(a3, wh[3], accH[c]);
        }
    }
    __syncthreads();                    // done reading sIn

    // Xb (bf16) staged via u32 view
    {
        uint32_t (*sOutU)[33] = (uint32_t (*)[33])&sIn[0][0];
#pragma unroll
        for (int c2 = 0; c2 < 8; ++c2)
            sOutU[row][q * 8 + c2] =
                (uint32_t)f2bf(accX[2*c2]) | ((uint32_t)f2bf(accX[2*c2+1]) << 16);
        __syncthreads();
        uint32_t* outU = (uint32_t*)Xb;
        int vu = vr * (DD / 2);
#pragma unroll
        for (int k = 0; k < 8; ++k) {
            int u = t + k * 256;
            if (u < vu) outU[(size_t)r0 * (DD / 2) + u] = sOutU[u >> 5][u & 31];
        }
    }
    __syncthreads();

    // HWh (f32) staged
    {
#pragma unroll
        for (int c = 0; c < 16; ++c) sIn[row][q * 16 + c] = accH[c];
        __syncthreads();
        float4* out4 = (float4*)HWh;
        int vf = vr * (DD / 4);
#pragma unroll
        for (int k = 0; k < 4; ++k) {
            int f = t + k * 256;
            if (f < vf) {
                int rr = f >> 4, c4 = (f & 15) * 4;
                float4 v;
                v.x = sIn[rr][c4]; v.y = sIn[rr][c4+1];
                v.z = sIn[rr][c4+2]; v.w = sIn[rr][c4+3];
                out4[(size_t)r0 * (DD / 4) + f] = v;
            }
        }
    }
}

// K2: histogram of obj + emit compact keys (pay | obj<<32).
// Fully-coalesced int4 reads, 2 edges per thread (edge row = 6 ints).
__global__ __launch_bounds__(256) void hist_emit(
    const int4* __restrict__ edges4, int* __restrict__ counts,
    uint64_t* __restrict__ keys, int n_edge)
{
    int t = blockIdx.x * 256 + threadIdx.x;
    int e0 = 2 * t;
    if (e0 >= n_edge) return;
    int4 a = edges4[3 * t];          // e0: r_idx, head, rel, tail
    int4 b = edges4[3 * t + 1];      // e0: sub, obj ; e1: r_idx, head
    // edge e0
    {
        uint32_t pay = (uint32_t)b.x | ((uint32_t)a.z << 17) | ((uint32_t)a.x << 26);
        atomicAdd(&counts[b.y], 1);
        keys[e0] = (uint64_t)pay | ((uint64_t)(uint32_t)b.y << 32);
    }
    // edge e0+1
    if (e0 + 1 < n_edge) {
        int4 c = edges4[3 * t + 2];  // e1: rel, tail, sub, obj
        uint32_t pay = (uint32_t)c.z | ((uint32_t)c.x << 17) | ((uint32_t)b.z << 26);
        atomicAdd(&counts[c.w], 1);
        keys[e0 + 1] = (uint64_t)pay | ((uint64_t)(uint32_t)c.w << 32);
    }
}

// K3: per-chunk exclusive scan (chunk = 1024), block-local excl + block sums
__global__ __launch_bounds__(1024) void scan1(
    const int* __restrict__ counts, int* __restrict__ offsets,
    int* __restrict__ bsums, int n)
{
    __shared__ int wsum[16];
    int t = threadIdx.x, i = blockIdx.x * 1024 + t;
    int lane = t & 63, wid = t >> 6;
    int c = (i < n) ? counts[i] : 0;
    int v = c;
#pragma unroll
    for (int d = 1; d < 64; d <<= 1) { int u = __shfl_up(v, d); if (lane >= d) v += u; }
    if (lane == 63) wsum[wid] = v;
    __syncthreads();
    if (wid == 0) {
        int s = (lane < 16) ? wsum[lane] : 0;
#pragma unroll
        for (int d = 1; d < 16; d <<= 1) { int u = __shfl_up(s, d); if (lane >= d) s += u; }
        if (lane < 16) wsum[lane] = s;
    }
    __syncthreads();
    int woff = (wid == 0) ? 0 : wsum[wid - 1];
    if (i < n) offsets[i] = woff + v - c;
    if (t == 1023) bsums[blockIdx.x] = wsum[15];
}

// K4: parallel single-block exclusive scan of block sums (nb <= 1024)
__global__ __launch_bounds__(1024) void scan_small(
    const int* __restrict__ bsums, int* __restrict__ boffs, int nb)
{
    __shared__ int wsum[16];
    int t = threadIdx.x, lane = t & 63, wid = t >> 6;
    int c = (t < nb) ? bsums[t] : 0;
    int v = c;
#pragma unroll
    for (int d = 1; d < 64; d <<= 1) { int u = __shfl_up(v, d); if (lane >= d) v += u; }
    if (lane == 63) wsum[wid] = v;
    __syncthreads();
    if (wid == 0) {
        int s = (lane < 16) ? wsum[lane] : 0;
#pragma unroll
        for (int d = 1; d < 16; d <<= 1) { int u = __shfl_up(s, d); if (lane >= d) s += u; }
        if (lane < 16) wsum[lane] = s;
    }
    __syncthreads();
    int woff = (wid == 0) ? 0 : wsum[wid - 1];
    if (t < nb) boffs[t] = woff + v - c;
}

// K5: add block offsets; init cursor
__global__ __launch_bounds__(1024) void scan3(
    int* __restrict__ offsets, int* __restrict__ cursor,
    const int* __restrict__ boffs, int n)
{
    int i = blockIdx.x * 1024 + threadIdx.x;
    if (i < n) {
        int v = offsets[i] + boffs[blockIdx.x];
        offsets[i] = v;
        cursor[i] = v;
    }
}

// K6: node_of_pos[offsets[n] .. offsets[n]+counts[n]) = n
__global__ __launch_bounds__(256) void fill_runs(
    const int* __restrict__ offsets, const int* __restrict__ counts,
    uint32_t* __restrict__ node_of_pos, int n_node)
{
    int n = blockIdx.x * 256 + threadIdx.x;
    if (n >= n_node) return;
    int s = offsets[n], c = counts[n];
    for (int i = 0; i < c; ++i) node_of_pos[s + i] = (uint32_t)n;
}

// K7: counting-sort: scatter u32 payload only (obj recoverable from position)
__global__ __launch_bounds__(256) void build_sorted(
    const uint64_t* __restrict__ keys, int* __restrict__ cursor,
    uint32_t* __restrict__ sorted_pay, int n_edge)
{
    int e = blockIdx.x * 256 + threadIdx.x;
    if (e >= n_edge) return;
    uint64_t k = keys[e];
    int obj = (int)(k >> 32);
    int pos = atomicAdd(&cursor[obj], 1);
    sorted_pay[pos] = (uint32_t)k;
}

// K8: fused alpha + segmented aggregation DIRECTLY into out (Wh folded in via
// HWh/RWh tables). One wave per 32 obj-sorted edges; per-edge scalars via
// v_readlane. Phase A (lane=feature): relu(x+c+q)*wa -> LDS f16.
// Phase B (lane=edge&31, half=lane>>5): row-sum + 1 shfl -> alpha.
// Phase C (lane=feature): out += alpha*(HWh[sub]+RWh[rel]), plain store
// interior segments / atomic at chunk boundaries.
__global__ __launch_bounds__(256, 4) void fused_aggregate(
    const uint32_t* __restrict__ sorted_pay, const uint32_t* __restrict__ node_of_pos,
    const uint16_t* __restrict__ Xb, const float* __restrict__ HWh,
    const float* __restrict__ Cf, const float* __restrict__ RWh,
    const float* __restrict__ walpha_w, const float* __restrict__ walpha_b,
    float* __restrict__ out, int n_edge, int n_node)
{
    __shared__ float sQ[N_QR * DD];               // 2 KB
    __shared__ __half sS[WPB][CHUNK][DD + 2];     // 16.9 KB
    int tid = threadIdx.x, lane = tid & 63, wid = tid >> 6;
    for (int i = tid; i < N_QR * DD; i += 64 * WPB) sQ[i] = Cf[N_RELTAB * DD + i];
    __syncthreads();

    long chunk = (long)blockIdx.x * WPB + wid;
    long base = chunk * CHUNK;
    if (base >= n_edge) return;

    int e_l = (int)base + (lane & 31);
    uint32_t pay = 0;
    int obj = n_node;                              // sentinel
    if (lane < 32 && e_l < n_edge) {
        pay = sorted_pay[e_l];
        obj = (int)node_of_pos[e_l];
    }

    float wa = walpha_w[lane];
    float wb = walpha_b[0];

    // ---- Phase A ----
#pragma unroll 8
    for (int j = 0; j < CHUNK; ++j) {
        uint32_t pj = (uint32_t)__builtin_amdgcn_readlane((int)pay, j);
        int sub  = (int)(pj & 0x1FFFFu);
        int rel  = (int)((pj >> 17) & 0x1FFu);
        int ridx = (int)((pj >> 26) & 7u);
        float x = bf2f(Xb[((size_t)sub << 6) + lane]);
        float c = Cf[(rel << 6) + lane];
        float q = sQ[(ridx << 6) + lane];
        sS[wid][j][lane] = __float2half(fmaxf(x + c + q, 0.f) * wa);
    }

    // ---- Phase B ----
    int eb = lane & 31, hb = lane >> 5;
    const __half2* row2 = (const __half2*)&sS[wid][eb][hb * 32];
    float tsum = 0.f;
#pragma unroll
    for (int a2 = 0; a2 < 16; ++a2) {
        float2 f = __half22float2(row2[a2]);
        tsum += f.x + f.y;
    }
    tsum += __shfl_xor(tsum, 32);
    float alpha = 1.f / (1.f + __expf(-(tsum + wb)));   // lanes j, j+32 hold edge j

    // ---- Phase C ----
    float acc = 0.f;
    int prev = __builtin_amdgcn_readlane(obj, 0);
    bool first = true;
#pragma unroll 8
    for (int j = 0; j < CHUNK; ++j) {
        int oj = __builtin_amdgcn_readlane(obj, j);
        if (oj != prev) {
            if (prev < n_node) {
                float* dst = &out[((size_t)prev << 6) + lane];
                if (first) atomicAdd(dst, acc); else *dst = acc;
            }
            first = false; acc = 0.f; prev = oj;
        }
        if (oj < n_node) {
            uint32_t pj = (uint32_t)__builtin_amdgcn_readlane((int)pay, j);
            int sub = (int)(pj & 0x1FFFFu);
            int rel = (int)((pj >> 17) & 0x1FFu);
            float h = HWh[((size_t)sub << 6) + lane];
            float r = RWh[(rel << 6) + lane];
            float aj = __uint_as_float(
                (uint32_t)__builtin_amdgcn_readlane((int)__float_as_uint(alpha), j));
            acc = fmaf(aj, h + r, acc);
        }
    }
    if (prev < n_node) atomicAdd(&out[((size_t)prev << 6) + lane], acc);
}

extern "C" void kernel_launch(void* const* d_in, const int* in_sizes, int n_in,
                              void* d_out, int out_size, void* d_ws, size_t ws_size,
                              hipStream_t stream)
{
    const int*   q_rel    = (const int*)d_in[1];
    const float* hidden   = (const float*)d_in[2];
    const int*   edges    = (const int*)d_in[3];
    const float* rel_emb  = (const float*)d_in[7];
    const float* Ws       = (const float*)d_in[8];
    const float* Wr       = (const float*)d_in[9];
    const float* Wqr_w    = (const float*)d_in[10];
    const float* Wqr_b    = (const float*)d_in[11];
    const float* walpha_w = (const float*)d_in[12];
    const float* walpha_b = (const float*)d_in[13];
    const float* Wh       = (const float*)d_in[14];
    float* out = (float*)d_out;

    const int n_node = in_sizes[2] / DD;   // 100000
    const int n_edge = in_sizes[3] / 6;    // 1000000
    const int NB = (n_node + 1023) / 1024; // scan chunks (98)

    // ws layout (all segments 64 B multiples), ~55 MB total:
    char* w = (char*)d_ws;
    uint16_t* Xb      = (uint16_t*)w;  w += (size_t)n_node * DD * 2;   // 12.8 MB
    float*    HWh     = (float*)w;     w += (size_t)n_node * DD * 4;   // 25.6 MB
    uint64_t* keys    = (uint64_t*)w;  w += (size_t)n_edge * 8;        // 8 MB
    uint32_t* spay    = (uint32_t*)w;  w += (size_t)n_edge * 4;        // 4 MB
    uint32_t* npos    = (uint32_t*)w;  w += (size_t)n_edge * 4;        // 4 MB
    int*      counts  = (int*)w;       w += (size_t)n_node * 4;
    int*      offsets = (int*)w;       w += (size_t)n_node * 4;
    int*      cursor  = (int*)w;       w += (size_t)n_node * 4;
    int*      bsums   = (int*)w;       w += 4096;
    int*      boffs   = (int*)w;       w += 4096;
    float*    Cf      = (float*)w;     w += (size_t)T_ROWS * DD * 4;   // 104.7 KB
    float*    RWh     = (float*)w;     w += (size_t)N_RELTAB * DD * 4; // 102.7 KB

    build_tables<<<T_ROWS, 64, 0, stream>>>(rel_emb, Wr, Wqr_w, Wqr_b, q_rel, Wh,
                                            Cf, RWh);
    prep<<<(n_node + DD - 1) / DD, 256, 0, stream>>>(hidden, Ws, Wh, Xb, HWh, n_node);
    hipMemsetAsync(counts, 0, (size_t)n_node * 4, stream);
    hipMemsetAsync(out, 0, (size_t)out_size * 4, stream);
    const int npair = (n_edge + 1) / 2;
    hist_emit<<<(npair + 255) / 256, 256, 0, stream>>>(
        (const int4*)edges, counts, keys, n_edge);
    scan1<<<NB, 1024, 0, stream>>>(counts, offsets, bsums, n_node);
    scan_small<<<1, 1024, 0, stream>>>(bsums, boffs, NB);
    scan3<<<NB, 1024, 0, stream>>>(offsets, cursor, boffs, n_node);
    fill_runs<<<(n_node + 255) / 256, 256, 0, stream>>>(offsets, counts, npos, n_node);
    build_sorted<<<(n_edge + 255) / 256, 256, 0, stream>>>(keys, cursor, spay, n_edge);
    const int nchunks = (n_edge + CHUNK - 1) / CHUNK;       // 31250
    fused_aggregate<<<(nchunks + WPB - 1) / WPB, 64 * WPB, 0, stream>>>(
        spay, npos, Xb, HWh, Cf, RWh, walpha_w, walpha_b, out, n_edge, n_node);
}

// Round 8
// 371.860 us; speedup vs baseline: 1.2384x; 1.1338x over previous
//
#include <hip/hip_runtime.h>
#include <hip/hip_fp16.h>
#include <cstdint>
#include <cstddef>

// Problem constants (fixed by the reference generator)
#define DD 64           // feature dim D == A
#define N_RELTAB 401    // rel_emb rows
#define N_QR 8          // batchsize B
#define T_ROWS (N_RELTAB + N_QR)   // 409 f32 rows: C[0..400], Q[401..408]
#define CHUNK 32        // edges per wave in fused_aggregate
#define WPB 4           // waves per block in fused_aggregate

__device__ __forceinline__ uint16_t f2bf(float f) {
    uint32_t u = __float_as_uint(f);
    u += 0x7fffu + ((u >> 16) & 1u);     // RNE
    return (uint16_t)(u >> 16);
}
__device__ __forceinline__ float bf2f(uint16_t u) {
    return __uint_as_float(((uint32_t)u) << 16);
}

// K0: Cf[r]  = Wr . rel_emb[r]                      (r < 401)
//     Cf[401+k] = Wqr . rel_emb[q_rel[k]] + Wqr_b   (k < 8)
//     RWh[r] = Wh . rel_emb[r]                      (r < 401)   (all f32)
__global__ __launch_bounds__(64) void build_tables(
    const float* __restrict__ rel_emb, const float* __restrict__ Wr,
    const float* __restrict__ Wqr_w, const float* __restrict__ Wqr_b,
    const int* __restrict__ q_rel, const float* __restrict__ Wh,
    float* __restrict__ Cf, float* __restrict__ RWh)
{
    int r = blockIdx.x, a = threadIdx.x;
    if (r < N_RELTAB) {
        const float* src = rel_emb + r * DD;
        const float* w1 = Wr + a * DD;
        const float* w2 = Wh + a * DD;
        float a1 = 0.f, a2 = 0.f;
#pragma unroll
        for (int d = 0; d < DD; ++d) {
            float s = src[d];
            a1 = fmaf(s, w1[d], a1);
            a2 = fmaf(s, w2[d], a2);
        }
        Cf[r * DD + a] = a1;
        RWh[r * DD + a] = a2;
    } else {
        int k = r - N_RELTAB;
        const float* src = rel_emb + q_rel[k] * DD;  // block-uniform
        const float* w = Wqr_w + a * DD;
        float acc = Wqr_b[a];
#pragma unroll
        for (int d = 0; d < DD; ++d) acc = fmaf(src[d], w[d], acc);
        Cf[r * DD + a] = acc;
    }
}

// K1: single pass over hidden -> Xb (bf16, Ws.h) and HWh (f32, Wh.h).
// 64 rows / block of 256; coalesced stage-in via LDS.
// Weight base goes through readfirstlane so the compiler PROVES uniformity
// and emits s_load (SMEM) for all W accesses — this was the round-6 bug:
// q = tid>>6 is wave-uniform in fact but not provably, so W reads were
// per-lane global_load_dwordx4 (~200M redundant VMEM ops/dispatch).
__global__ __launch_bounds__(256) void prep(
    const float* __restrict__ in, const float* __restrict__ Ws,
    const float* __restrict__ Wh, uint16_t* __restrict__ Xb,
    float* __restrict__ HWh, int nrows)
{
    __shared__ float sIn[DD][DD + 1];   // 16.6 KB; reused for out staging
    int r0 = blockIdx.x * DD;
    int t = threadIdx.x;
    int vr = nrows - r0; if (vr > DD) vr = DD;

    const float4* gin = (const float4*)(in + (size_t)r0 * DD);
    int vf4 = vr * (DD / 4);
#pragma unroll
    for (int k = 0; k < 4; ++k) {
        int f = t + k * 256;
        float4 v = (f < vf4) ? gin[f] : make_float4(0.f, 0.f, 0.f, 0.f);
        int row = f >> 4, c4 = (f & 15) * 4;
        sIn[row][c4] = v.x; sIn[row][c4+1] = v.y; sIn[row][c4+2] = v.z; sIn[row][c4+3] = v.w;
    }
    __syncthreads();

    int row = t & 63, q = t >> 6;       // thread = (row, col-quarter)
    int qu = __builtin_amdgcn_readfirstlane(q);   // SGPR: wave-uniform quarter
    float accX[16], accH[16];
#pragma unroll
    for (int c = 0; c < 16; ++c) { accX[c] = 0.f; accH[c] = 0.f; }
    const float* wqX = Ws + (qu * 16) * DD;
    const float* wqH = Wh + (qu * 16) * DD;
    for (int d4 = 0; d4 < 16; ++d4) {
        float a0 = sIn[row][4*d4+0], a1 = sIn[row][4*d4+1];
        float a2 = sIn[row][4*d4+2], a3 = sIn[row][4*d4+3];
#pragma unroll
        for (int c = 0; c < 16; ++c) {
            const float* wx = wqX + c * DD + d4 * 4;   // SGPR base -> s_load
            const float* wh = wqH + c * DD + d4 * 4;
            accX[c] = fmaf(a0, wx[0], accX[c]);
            accX[c] = fmaf(a1, wx[1], accX[c]);
            accX[c] = fmaf(a2, wx[2], accX[c]);
            accX[c] = fmaf(a3, wx[3], accX[c]);
            accH[c] = fmaf(a0, wh[0], accH[c]);
            accH[c] = fmaf(a1, wh[1], accH[c]);
            accH[c] = fmaf(a2, wh[2], accH[c]);
            accH[c] = fmaf(a3, wh[3], accH[c]);
        }
    }
    __syncthreads();                    // done reading sIn

    // Xb (bf16) staged via u32 view
    {
        uint32_t (*sOutU)[33] = (uint32_t (*)[33])&sIn[0][0];
#pragma unroll
        for (int c2 = 0; c2 < 8; ++c2)
            sOutU[row][qu * 8 + c2] =
                (uint32_t)f2bf(accX[2*c2]) | ((uint32_t)f2bf(accX[2*c2+1]) << 16);
        __syncthreads();
        uint32_t* outU = (uint32_t*)Xb;
        int vu = vr * (DD / 2);
#pragma unroll
        for (int k = 0; k < 8; ++k) {
            int u = t + k * 256;
            if (u < vu) outU[(size_t)r0 * (DD / 2) + u] = sOutU[u >> 5][u & 31];
        }
    }
    __syncthreads();

    // HWh (f32) staged
    {
#pragma unroll
        for (int c = 0; c < 16; ++c) sIn[row][qu * 16 + c] = accH[c];
        __syncthreads();
        float4* out4 = (float4*)HWh;
        int vf = vr * (DD / 4);
#pragma unroll
        for (int k = 0; k < 4; ++k) {
            int f = t + k * 256;
            if (f < vf) {
                int rr = f >> 4, c4 = (f & 15) * 4;
                float4 v;
                v.x = sIn[rr][c4]; v.y = sIn[rr][c4+1];
                v.z = sIn[rr][c4+2]; v.w = sIn[rr][c4+3];
                out4[(size_t)r0 * (DD / 4) + f] = v;
            }
        }
    }
}

// K2: histogram of obj + emit compact keys (pay | obj<<32).
// Fully-coalesced int4 reads, 2 edges per thread (edge row = 6 ints).
__global__ __launch_bounds__(256) void hist_emit(
    const int4* __restrict__ edges4, int* __restrict__ counts,
    uint64_t* __restrict__ keys, int n_edge)
{
    int t = blockIdx.x * 256 + threadIdx.x;
    int e0 = 2 * t;
    if (e0 >= n_edge) return;
    int4 a = edges4[3 * t];          // e0: r_idx, head, rel, tail
    int4 b = edges4[3 * t + 1];      // e0: sub, obj ; e1: r_idx, head
    // edge e0
    {
        uint32_t pay = (uint32_t)b.x | ((uint32_t)a.z << 17) | ((uint32_t)a.x << 26);
        atomicAdd(&counts[b.y], 1);
        keys[e0] = (uint64_t)pay | ((uint64_t)(uint32_t)b.y << 32);
    }
    // edge e0+1
    if (e0 + 1 < n_edge) {
        int4 c = edges4[3 * t + 2];  // e1: rel, tail, sub, obj
        uint32_t pay = (uint32_t)c.z | ((uint32_t)c.x << 17) | ((uint32_t)b.z << 26);
        atomicAdd(&counts[c.w], 1);
        keys[e0 + 1] = (uint64_t)pay | ((uint64_t)(uint32_t)c.w << 32);
    }
}

// K3: per-chunk exclusive scan (chunk = 1024), block-local excl + block sums
__global__ __launch_bounds__(1024) void scan1(
    const int* __restrict__ counts, int* __restrict__ offsets,
    int* __restrict__ bsums, int n)
{
    __shared__ int wsum[16];
    int t = threadIdx.x, i = blockIdx.x * 1024 + t;
    int lane = t & 63, wid = t >> 6;
    int c = (i < n) ? counts[i] : 0;
    int v = c;
#pragma unroll
    for (int d = 1; d < 64; d <<= 1) { int u = __shfl_up(v, d); if (lane >= d) v += u; }
    if (lane == 63) wsum[wid] = v;
    __syncthreads();
    if (wid == 0) {
        int s = (lane < 16) ? wsum[lane] : 0;
#pragma unroll
        for (int d = 1; d < 16; d <<= 1) { int u = __shfl_up(s, d); if (lane >= d) s += u; }
        if (lane < 16) wsum[lane] = s;
    }
    __syncthreads();
    int woff = (wid == 0) ? 0 : wsum[wid - 1];
    if (i < n) offsets[i] = woff + v - c;
    if (t == 1023) bsums[blockIdx.x] = wsum[15];
}

// K4: parallel single-block exclusive scan of block sums (nb <= 1024)
__global__ __launch_bounds__(1024) void scan_small(
    const int* __restrict__ bsums, int* __restrict__ boffs, int nb)
{
    __shared__ int wsum[16];
    int t = threadIdx.x, lane = t & 63, wid = t >> 6;
    int c = (t < nb) ? bsums[t] : 0;
    int v = c;
#pragma unroll
    for (int d = 1; d < 64; d <<= 1) { int u = __shfl_up(v, d); if (lane >= d) v += u; }
    if (lane == 63) wsum[wid] = v;
    __syncthreads();
    if (wid == 0) {
        int s = (lane < 16) ? wsum[lane] : 0;
#pragma unroll
        for (int d = 1; d < 16; d <<= 1) { int u = __shfl_up(s, d); if (lane >= d) s += u; }
        if (lane < 16) wsum[lane] = s;
    }
    __syncthreads();
    int woff = (wid == 0) ? 0 : wsum[wid - 1];
    if (t < nb) boffs[t] = woff + v - c;
}

// K5: add block offsets; init cursor; fill node_of_pos runs (merged fill_runs)
__global__ __launch_bounds__(1024) void scan3_fill(
    int* __restrict__ offsets, int* __restrict__ cursor,
    const int* __restrict__ boffs, const int* __restrict__ counts,
    uint32_t* __restrict__ node_of_pos, int n)
{
    int i = blockIdx.x * 1024 + threadIdx.x;
    if (i < n) {
        int v = offsets[i] + boffs[blockIdx.x];
        offsets[i] = v;
        cursor[i] = v;
        int c = counts[i];
        for (int k = 0; k < c; ++k) node_of_pos[v + k] = (uint32_t)i;
    }
}

// K6: counting-sort: scatter u32 payload only (obj recoverable from position)
__global__ __launch_bounds__(256) void build_sorted(
    const uint64_t* __restrict__ keys, int* __restrict__ cursor,
    uint32_t* __restrict__ sorted_pay, int n_edge)
{
    int e = blockIdx.x * 256 + threadIdx.x;
    if (e >= n_edge) return;
    uint64_t k = keys[e];
    int obj = (int)(k >> 32);
    int pos = atomicAdd(&cursor[obj], 1);
    sorted_pay[pos] = (uint32_t)k;
}

// K7: fused alpha + segmented aggregation DIRECTLY into out (Wh folded in via
// HWh/RWh tables). One wave per 32 obj-sorted edges; per-edge scalars via
// v_readlane. Phase A (lane=feature): relu(x+c+q)*wa -> LDS f16.
// Phase B (lane=edge&31, half=lane>>5): row-sum + 1 shfl -> alpha.
// Phase C (lane=feature): out += alpha*(HWh[sub]+RWh[rel]), plain store
// interior segments / atomic at chunk boundaries.
__global__ __launch_bounds__(256, 4) void fused_aggregate(
    const uint32_t* __restrict__ sorted_pay, const uint32_t* __restrict__ node_of_pos,
    const uint16_t* __restrict__ Xb, const float* __restrict__ HWh,
    const float* __restrict__ Cf, const float* __restrict__ RWh,
    const float* __restrict__ walpha_w, const float* __restrict__ walpha_b,
    float* __restrict__ out, int n_edge, int n_node)
{
    __shared__ float sQ[N_QR * DD];               // 2 KB
    __shared__ __half sS[WPB][CHUNK][DD + 2];     // 16.9 KB
    int tid = threadIdx.x, lane = tid & 63, wid = tid >> 6;
    for (int i = tid; i < N_QR * DD; i += 64 * WPB) sQ[i] = Cf[N_RELTAB * DD + i];
    __syncthreads();

    long chunk = (long)blockIdx.x * WPB + wid;
    long base = chunk * CHUNK;
    if (base >= n_edge) return;

    int e_l = (int)base + (lane & 31);
    uint32_t pay = 0;
    int obj = n_node;                              // sentinel
    if (lane < 32 && e_l < n_edge) {
        pay = sorted_pay[e_l];
        obj = (int)node_of_pos[e_l];
    }

    float wa = walpha_w[lane];
    float wb = walpha_b[0];

    // ---- Phase A ----
#pragma unroll 8
    for (int j = 0; j < CHUNK; ++j) {
        uint32_t pj = (uint32_t)__builtin_amdgcn_readlane((int)pay, j);
        int sub  = (int)(pj & 0x1FFFFu);
        int rel  = (int)((pj >> 17) & 0x1FFu);
        int ridx = (int)((pj >> 26) & 7u);
        float x = bf2f(Xb[((size_t)sub << 6) + lane]);
        float c = Cf[(rel << 6) + lane];
        float q = sQ[(ridx << 6) + lane];
        sS[wid][j][lane] = __float2half(fmaxf(x + c + q, 0.f) * wa);
    }

    // ---- Phase B ----
    int eb = lane & 31, hb = lane >> 5;
    const __half2* row2 = (const __half2*)&sS[wid][eb][hb * 32];
    float tsum = 0.f;
#pragma unroll
    for (int a2 = 0; a2 < 16; ++a2) {
        float2 f = __half22float2(row2[a2]);
        tsum += f.x + f.y;
    }
    tsum += __shfl_xor(tsum, 32);
    float alpha = 1.f / (1.f + __expf(-(tsum + wb)));   // lanes j, j+32 hold edge j

    // ---- Phase C ----
    float acc = 0.f;
    int prev = __builtin_amdgcn_readlane(obj, 0);
    bool first = true;
#pragma unroll 8
    for (int j = 0; j < CHUNK; ++j) {
        int oj = __builtin_amdgcn_readlane(obj, j);
        if (oj != prev) {
            if (prev < n_node) {
                float* dst = &out[((size_t)prev << 6) + lane];
                if (first) atomicAdd(dst, acc); else *dst = acc;
            }
            first = false; acc = 0.f; prev = oj;
        }
        if (oj < n_node) {
            uint32_t pj = (uint32_t)__builtin_amdgcn_readlane((int)pay, j);
            int sub = (int)(pj & 0x1FFFFu);
            int rel = (int)((pj >> 17) & 0x1FFu);
            float h = HWh[((size_t)sub << 6) + lane];
            float r = RWh[(rel << 6) + lane];
            float aj = __uint_as_float(
                (uint32_t)__builtin_amdgcn_readlane((int)__float_as_uint(alpha), j));
            acc = fmaf(aj, h + r, acc);
        }
    }
    if (prev < n_node) atomicAdd(&out[((size_t)prev << 6) + lane], acc);
}

extern "C" void kernel_launch(void* const* d_in, const int* in_sizes, int n_in,
                              void* d_out, int out_size, void* d_ws, size_t ws_size,
                              hipStream_t stream)
{
    const int*   q_rel    = (const int*)d_in[1];
    const float* hidden   = (const float*)d_in[2];
    const int*   edges    = (const int*)d_in[3];
    const float* rel_emb  = (const float*)d_in[7];
    const float* Ws       = (const float*)d_in[8];
    const float* Wr       = (const float*)d_in[9];
    const float* Wqr_w    = (const float*)d_in[10];
    const float* Wqr_b    = (const float*)d_in[11];
    const float* walpha_w = (const float*)d_in[12];
    const float* walpha_b = (const float*)d_in[13];
    const float* Wh       = (const float*)d_in[14];
    float* out = (float*)d_out;

    const int n_node = in_sizes[2] / DD;   // 100000
    const int n_edge = in_sizes[3] / 6;    // 1000000
    const int NB = (n_node + 1023) / 1024; // scan chunks (98)

    // ws layout (all segments 64 B multiples), ~55 MB total:
    char* w = (char*)d_ws;
    uint16_t* Xb      = (uint16_t*)w;  w += (size_t)n_node * DD * 2;   // 12.8 MB
    float*    HWh     = (float*)w;     w += (size_t)n_node * DD * 4;   // 25.6 MB
    uint64_t* keys    = (uint64_t*)w;  w += (size_t)n_edge * 8;        // 8 MB
    uint32_t* spay    = (uint32_t*)w;  w += (size_t)n_edge * 4;        // 4 MB
    uint32_t* npos    = (uint32_t*)w;  w += (size_t)n_edge * 4;        // 4 MB
    int*      counts  = (int*)w;       w += (size_t)n_node * 4;
    int*      offsets = (int*)w;       w += (size_t)n_node * 4;
    int*      cursor  = (int*)w;       w += (size_t)n_node * 4;
    int*      bsums   = (int*)w;       w += 4096;
    int*      boffs   = (int*)w;       w += 4096;
    float*    Cf      = (float*)w;     w += (size_t)T_ROWS * DD * 4;   // 104.7 KB
    float*    RWh     = (float*)w;     w += (size_t)N_RELTAB * DD * 4; // 102.7 KB

    build_tables<<<T_ROWS, 64, 0, stream>>>(rel_emb, Wr, Wqr_w, Wqr_b, q_rel, Wh,
                                            Cf, RWh);
    prep<<<(n_node + DD - 1) / DD, 256, 0, stream>>>(hidden, Ws, Wh, Xb, HWh, n_node);
    hipMemsetAsync(counts, 0, (size_t)n_node * 4, stream);
    hipMemsetAsync(out, 0, (size_t)out_size * 4, stream);
    const int npair = (n_edge + 1) / 2;
    hist_emit<<<(npair + 255) / 256, 256, 0, stream>>>(
        (const int4*)edges, counts, keys, n_edge);
    scan1<<<NB, 1024, 0, stream>>>(counts, offsets, bsums, n_node);
    scan_small<<<1, 1024, 0, stream>>>(bsums, boffs, NB);
    scan3_fill<<<NB, 1024, 0, stream>>>(offsets, cursor, boffs, counts, npos, n_node);
    build_sorted<<<(n_edge + 255) / 256, 256, 0, stream>>>(keys, cursor, spay, n_edge);
    const int nchunks = (n_edge + CHUNK - 1) / CHUNK;       // 31250
    fused_aggregate<<<(nchunks + WPB - 1) / WPB, 64 * WPB, 0, stream>>>(
        spay, npos, Xb, HWh, Cf, RWh, walpha_w, walpha_b, out, n_edge, n_node);
}